// Round 5
// baseline (145.942 us; speedup 1.0000x reference)
//
#include <hip/hip_runtime.h>

// Problem constants
#define BATCH   8
#define NNODES  16384
#define KNBR    16
#define LATENT  128
#define DOUT    32
#define NROWS   (BATCH * NNODES)          // 131072 rows

typedef __attribute__((ext_vector_type(8))) short short8;   // 8 bf16 (4 VGPRs)
typedef __attribute__((ext_vector_type(4))) float floatx4;  // MFMA acc

__device__ __forceinline__ unsigned short f2bf(float f) {   // fp32 -> bf16 RNE
    unsigned u = __float_as_uint(f);
    u += 0x7fff + ((u >> 16) & 1);
    return (unsigned short)(u >> 16);
}

__device__ __forceinline__ unsigned pack2bf(float a, float b) {
    return (unsigned)f2bf(a) | ((unsigned)f2bf(b) << 16);
}

__device__ __forceinline__ float dot2bf(unsigned a, unsigned b) {
    float alo = __uint_as_float(a << 16);
    float ahi = __uint_as_float(a & 0xffff0000u);
    float blo = __uint_as_float(b << 16);
    float bhi = __uint_as_float(b & 0xffff0000u);
    return alo * blo + ahi * bhi;
}

#define BPAD 136    // B row stride: 128 + 8 bf16 (272 B)

// ---------------------------------------------------------------------------
// Kernel 1 (v4): bf16 MFMA projection, A DIRECT global->VGPR (no LDS for A).
// Rationale: zero cross-wave A-reuse -> LDS staging of A bought nothing and
// cost 4 barriers/tile + 32 KB LDS. The MFMA A-fragment (lane (m,q) holds
// A[m][ks*32+q*8 .. +7]) is a coalesced global pattern: per dwordx4 pair,
// 16 rows x 32 B fully-consumed contiguous segments. 16 independent loads
// per thread in flight; LDS holds only B (17 KB) -> 1 barrier per block.
// Tile->batch remap kept: block bid handles batch bid%8 so batch b's table
// lines are written on block-residue b (same XCD residue that gathers them).
// ---------------------------------------------------------------------------
__global__ __launch_bounds__(256) void proj_kernel(
    const float* __restrict__ feats,
    const float* __restrict__ kw, const float* __restrict__ kb,
    const float* __restrict__ qw, const float* __restrict__ qb,
    unsigned short* __restrict__ tkb, unsigned short* __restrict__ tqb)
{
    __shared__ unsigned short B_lds[64 * BPAD];              // 17 KB
    __shared__ float bias_lds[64];

    const int tid  = threadIdx.x;
    const int lane = tid & 63;
    const int w    = tid >> 6;                     // wave 0..3
    const int bat  = blockIdx.x & 7;               // batch == block residue
    const int u    = blockIdx.x >> 3;              // tile within batch, 0..127
    const long long blk_row = (long long)bat * NNODES + (long long)u * 128;

    // Stage B = [kw ; qw] as bf16: B_lds[col*BPAD + k] = W_cat[col][k]
    {
        const float4* kw4 = (const float4*)kw;     // [32 rows][32 f4]
        const float4* qw4 = (const float4*)qw;
#pragma unroll
        for (int i = 0; i < 8; ++i) {
            const int linear = i * 256 + tid;      // 0..2047
            const int row = linear >> 5;           // 0..63
            const int c4  = linear & 31;
            const float4 v = (row < 32) ? kw4[row * 32 + c4] : qw4[(row - 32) * 32 + c4];
            *(uint2*)&B_lds[row * BPAD + c4 * 4] =
                make_uint2(pack2bf(v.x, v.y), pack2bf(v.z, v.w));
        }
        if (tid < 64) bias_lds[tid] = (tid < 32) ? kb[tid] : qb[tid - 32];
    }

    const int m = lane & 15;   // MFMA row (A) / col (B,C)
    const int q = lane >> 4;   // quad

    // Issue all A loads: 2 row-tiles x 4 k-steps x 2 dwordx4, fully static.
    const float4* Ar0 = (const float4*)(feats + (blk_row + w * 32 + m) * 128);
    const float4* Ar1 = (const float4*)(feats + (blk_row + w * 32 + 16 + m) * 128);
    float4 araw[2][4][2];
#pragma unroll
    for (int ks = 0; ks < 4; ++ks) {
        const int f4o = ks * 8 + q * 2;            // float4 offset in row
        araw[0][ks][0] = Ar0[f4o];
        araw[0][ks][1] = Ar0[f4o + 1];
        araw[1][ks][0] = Ar1[f4o];
        araw[1][ks][1] = Ar1[f4o + 1];
    }

    // Convert to bf16 A-fragments (RNE, same numerics as before).
    short8 afr[2][4];
#pragma unroll
    for (int rt = 0; rt < 2; ++rt)
#pragma unroll
        for (int ks = 0; ks < 4; ++ks) {
            union { short8 s; unsigned uu[4]; } af;
            af.uu[0] = pack2bf(araw[rt][ks][0].x, araw[rt][ks][0].y);
            af.uu[1] = pack2bf(araw[rt][ks][0].z, araw[rt][ks][0].w);
            af.uu[2] = pack2bf(araw[rt][ks][1].x, araw[rt][ks][1].y);
            af.uu[3] = pack2bf(araw[rt][ks][1].z, araw[rt][ks][1].w);
            afr[rt][ks] = af.s;
        }

    __syncthreads();   // B/bias staged (once per block)

    floatx4 acc[2][4];
#pragma unroll
    for (int rt = 0; rt < 2; ++rt)
#pragma unroll
        for (int ct = 0; ct < 4; ++ct) acc[rt][ct] = (floatx4){0.f, 0.f, 0.f, 0.f};

#pragma unroll
    for (int ks = 0; ks < 4; ++ks) {
        const int kg = ks * 32 + q * 8;
        short8 bf[4];
#pragma unroll
        for (int ct = 0; ct < 4; ++ct)
            bf[ct] = *(const short8*)&B_lds[(ct * 16 + m) * BPAD + kg];
#pragma unroll
        for (int rt = 0; rt < 2; ++rt)
#pragma unroll
            for (int ct = 0; ct < 4; ++ct)
                acc[rt][ct] = __builtin_amdgcn_mfma_f32_16x16x32_bf16(afr[rt][ks], bf[ct], acc[rt][ct], 0, 0, 0);
    }

    // Epilogue: bias + bf16 store. C/D layout: col = lane&15, row = q*4+reg.
#pragma unroll
    for (int rt = 0; rt < 2; ++rt) {
#pragma unroll
        for (int reg = 0; reg < 4; ++reg) {
            const long long row = blk_row + w * 32 + rt * 16 + q * 4 + reg;
#pragma unroll
            for (int ct = 0; ct < 4; ++ct) {
                const float val = acc[rt][ct][reg] + bias_lds[ct * 16 + m];
                if (ct < 2) tkb[row * DOUT + ct * 16 + m]       = f2bf(val);
                else        tqb[row * DOUT + (ct - 2) * 16 + m] = f2bf(val);
            }
        }
    }
}

// ---------------------------------------------------------------------------
// Kernel 2: gather + scaled dot, cooperative-4 v2 (proven round 4).
// Thread tid owns output blkbase+tid: idx loads stride-1 coalesced with ZERO
// redundancy, final store fully dense (256 B/wave). Each quad processes its 4
// consecutive outputs over 4 passes; owner row index broadcast in-register
// via __shfl within the quad. Table rows read cooperative-4 (4 lanes x 16 B
// = one fully-consumed 64 B line per row). Tables L2-resident & XCD-local.
// ---------------------------------------------------------------------------
__global__ __launch_bounds__(256) void gather_dot_kernel(
    const unsigned short* __restrict__ tkb, const unsigned short* __restrict__ tqb,
    const int* __restrict__ idx, float* __restrict__ out)
{
    const long long NK  = (long long)NNODES * KNBR;     // 262144 per batch
    const long long BNK = NK * BATCH;                   // 2097152 total

    const int bat  = blockIdx.x & 7;
    const int blk  = blockIdx.x >> 3;                   // 0..1023
    const int tid  = threadIdx.x;
    const int lane = tid & 63;
    const int j    = tid & 3;                           // uint4 column in row

    const uint4* tb_k = (const uint4*)(tkb + (long long)bat * NNODES * DOUT);
    const uint4* tb_q = (const uint4*)(tqb + (long long)bat * NNODES * DOUT);

    const long long o0 = (long long)bat * NK + (long long)blk * 256 + tid;

    const int xi = __builtin_nontemporal_load(&idx[BNK + o0]);        // ch 1
    const int yi = __builtin_nontemporal_load(&idx[2 * BNK + o0]);    // ch 2

    float r0, r1, r2, r3;
#pragma unroll
    for (int p = 0; p < 4; ++p) {
        const int xp = __shfl(xi, (lane & ~3) | p);   // quad-owner broadcast
        const int yp = __shfl(yi, (lane & ~3) | p);
        const uint4 x = tb_k[(long long)xp * 4 + j];
        const uint4 y = tb_q[(long long)yp * 4 + j];
        float s = dot2bf(x.x, y.x) + dot2bf(x.y, y.y)
                + dot2bf(x.z, y.z) + dot2bf(x.w, y.w);
        s += __shfl_xor(s, 1);
        s += __shfl_xor(s, 2);   // all 4 lanes hold the full 32-dim sum
        if      (p == 0) r0 = s;
        else if (p == 1) r1 = s;
        else if (p == 2) r2 = s;
        else             r3 = s;
    }
    // lane j stores pass-j's result -> dense contiguous store
    const float v = (j == 0) ? r0 : (j == 1) ? r1 : (j == 2) ? r2 : r3;
    __builtin_nontemporal_store(v * 0.17677669529663687f, &out[o0]);  // 32^-0.5
}

// ---------------------------------------------------------------------------
extern "C" void kernel_launch(void* const* d_in, const int* in_sizes, int n_in,
                              void* d_out, int out_size, void* d_ws, size_t ws_size,
                              hipStream_t stream)
{
    const float* feats = (const float*)d_in[0];
    const float* kw    = (const float*)d_in[1];
    const float* kb    = (const float*)d_in[2];
    const float* qw    = (const float*)d_in[3];
    const float* qb    = (const float*)d_in[4];
    const int*   idx   = (const int*)d_in[5];
    float*       out   = (float*)d_out;

    // Workspace: two bf16 tables [B*N, 32] = 8 MB each
    unsigned short* tkb = (unsigned short*)d_ws;
    unsigned short* tqb = tkb + (long long)NROWS * DOUT;

    proj_kernel<<<NROWS / 128, 256, 0, stream>>>(feats, kw, kb, qw, qb, tkb, tqb);
    gather_dot_kernel<<<(int)((long long)BATCH * NNODES * KNBR / 256), 256, 0, stream>>>(
        tkb, tqb, idx, out);
}

// Round 6
// 142.778 us; speedup vs baseline: 1.0222x; 1.0222x over previous
//
#include <hip/hip_runtime.h>

// Problem constants
#define BATCH   8
#define NNODES  16384
#define KNBR    16
#define LATENT  128
#define DOUT    32
#define NROWS   (BATCH * NNODES)          // 131072 rows

typedef __attribute__((ext_vector_type(8))) short short8;   // 8 bf16 (4 VGPRs)
typedef __attribute__((ext_vector_type(4))) float floatx4;  // MFMA acc

__device__ __forceinline__ unsigned short f2bf(float f) {   // fp32 -> bf16 RNE
    unsigned u = __float_as_uint(f);
    u += 0x7fff + ((u >> 16) & 1);
    return (unsigned short)(u >> 16);
}

__device__ __forceinline__ float dot2bf(unsigned a, unsigned b) {
    float alo = __uint_as_float(a << 16);
    float ahi = __uint_as_float(a & 0xffff0000u);
    float blo = __uint_as_float(b << 16);
    float bhi = __uint_as_float(b & 0xffff0000u);
    return alo * blo + ahi * bhi;
}

// Direct global->LDS 16B copy (no VGPR round-trip). Size must be a literal.
__device__ __forceinline__ void gload_lds16(const float* g, void* l) {
    __builtin_amdgcn_global_load_lds(
        (const __attribute__((address_space(1))) void*)g,
        (__attribute__((address_space(3))) void*)l,
        16, 0, 0);
}

#define BPAD 136    // B row stride: 128 + 8 bf16 (272 B)

// ---------------------------------------------------------------------------
// Kernel 1: bf16 MFMA projection — EXACT round-4 structure (measured best;
// round-5's direct-VGPR A variant was -1.9us, reverted).
// 128 rows/block, 4 waves. A staged fp32 via global_load_lds(16B), XOR swizzle
// on BOTH sides (pre-swizzled global source + swizzled ds_read, rule #21):
//   phys(L) = L ^ ((row&7)<<4).
// Tile->batch remap: block bid handles batch bid%8 so batch b's table lines
// are written on block-residue b (same XCD residue that gathers them).
// ---------------------------------------------------------------------------
__global__ __launch_bounds__(256) void proj_kernel(
    const float* __restrict__ feats,
    const float* __restrict__ kw, const float* __restrict__ kb,
    const float* __restrict__ qw, const float* __restrict__ qb,
    unsigned short* __restrict__ tkb, unsigned short* __restrict__ tqb)
{
    __shared__ __align__(16) unsigned char A_raw[128 * 256]; // 32 KB fp32 chunk
    __shared__ unsigned short B_lds[64 * BPAD];              // 17 KB
    __shared__ float bias_lds[64];

    const int tid  = threadIdx.x;
    const int lane = tid & 63;
    const int w    = tid >> 6;                     // wave 0..3
    const int bat  = blockIdx.x & 7;               // batch == block residue
    const int u    = blockIdx.x >> 3;              // tile within batch, 0..127
    const long long blk_row = (long long)bat * NNODES + (long long)u * 128;

    // Stage B = [kw ; qw] as bf16: B_lds[col*BPAD + k] = W_cat[col][k]
    {
        const float4* kw4 = (const float4*)kw;     // [32 rows][32 f4]
        const float4* qw4 = (const float4*)qw;
#pragma unroll
        for (int i = 0; i < 8; ++i) {
            const int linear = i * 256 + tid;      // 0..2047
            const int row = linear >> 5;           // 0..63
            const int c4  = linear & 31;
            const float4 v = (row < 32) ? kw4[row * 32 + c4] : qw4[(row - 32) * 32 + c4];
            unsigned lo = f2bf(v.x) | ((unsigned)f2bf(v.y) << 16);
            unsigned hi = f2bf(v.z) | ((unsigned)f2bf(v.w) << 16);
            *(uint2*)&B_lds[row * BPAD + c4 * 4] = make_uint2(lo, hi);
        }
        if (tid < 64) bias_lds[tid] = (tid < 32) ? kb[tid] : qb[tid - 32];
    }

    const int m = lane & 15;   // MFMA row (A) / col (B,C)
    const int q = lane >> 4;   // quad

    floatx4 acc[2][4];
#pragma unroll
    for (int rt = 0; rt < 2; ++rt)
#pragma unroll
        for (int ct = 0; ct < 4; ++ct) acc[rt][ct] = (floatx4){0.f, 0.f, 0.f, 0.f};

    for (int ch = 0; ch < 2; ++ch) {
        if (ch) __syncthreads();   // prev chunk fully consumed before overwrite

        // Issue A-chunk staging: 128 rows x 64 fp32 = 32 KB, 8 x 16B/thread.
        // Dest L linear; source address is the element whose swizzled
        // position is L: col_bytes = (L&255) ^ ((row&7)<<4).
#pragma unroll
        for (int i = 0; i < 8; ++i) {
            const int L  = i * 4096 + tid * 16;
            const int r  = L >> 8;                              // 0..127
            const int c0 = (((L & 255) ^ ((r & 7) << 4)) >> 2); // fp32 col
            gload_lds16(feats + (blk_row + r) * 128 + ch * 64 + c0, A_raw + L);
        }
        __syncthreads();   // drains vmcnt -> chunk (and on ch0: B/bias) visible

#pragma unroll
        for (int ks = 0; ks < 2; ++ks) {
            const int kg = ch * 64 + ks * 32 + q * 8;  // global k for B
            short8 bf[4];
#pragma unroll
            for (int ct = 0; ct < 4; ++ct)
                bf[ct] = *(const short8*)&B_lds[(ct * 16 + m) * BPAD + kg];
#pragma unroll
            for (int rt = 0; rt < 2; ++rt) {
                const int rloc = w * 32 + rt * 16 + m;
                const int b0   = rloc * 256 + ks * 128 + q * 32;   // logical byte
                const int p0   = b0 ^ ((rloc & 7) << 4);           // swizzled
                const float4 a0 = *(const float4*)(A_raw + p0);
                const float4 a1 = *(const float4*)(A_raw + (p0 ^ 16));
                union { short8 s; unsigned uu[4]; } af;
                af.uu[0] = f2bf(a0.x) | ((unsigned)f2bf(a0.y) << 16);
                af.uu[1] = f2bf(a0.z) | ((unsigned)f2bf(a0.w) << 16);
                af.uu[2] = f2bf(a1.x) | ((unsigned)f2bf(a1.y) << 16);
                af.uu[3] = f2bf(a1.z) | ((unsigned)f2bf(a1.w) << 16);
#pragma unroll
                for (int ct = 0; ct < 4; ++ct)
                    acc[rt][ct] = __builtin_amdgcn_mfma_f32_16x16x32_bf16(af.s, bf[ct], acc[rt][ct], 0, 0, 0);
            }
        }
    }

    // Epilogue: bias + bf16 store. C/D layout: col = lane&15, row = q*4+reg.
#pragma unroll
    for (int rt = 0; rt < 2; ++rt) {
#pragma unroll
        for (int reg = 0; reg < 4; ++reg) {
            const long long row = blk_row + w * 32 + rt * 16 + q * 4 + reg;
#pragma unroll
            for (int ct = 0; ct < 4; ++ct) {
                const float val = acc[rt][ct][reg] + bias_lds[ct * 16 + m];
                if (ct < 2) tkb[row * DOUT + ct * 16 + m]       = f2bf(val);
                else        tqb[row * DOUT + (ct - 2) * 16 + m] = f2bf(val);
            }
        }
    }
}

// ---------------------------------------------------------------------------
// Kernel 2: gather + scaled dot, cooperative-4 v3 (grid-stride x4 for MLP).
// 2048 blocks (8/CU, full occupancy). Each thread owns 4 outputs at
// 65536-output stride: all 8 idx loads independent & issued up-front, then
// 32 table loads in flight (4x the MLP of v2), hiding L2 latency.
// Table rows still read cooperative-4 (4 lanes x 16 B = one fully-consumed
// 64 B line per row; 16 lines/instr — the shape round-3 proved optimal).
// idx loads stride-1 coalesced, zero redundancy; store fully dense.
// Tables L2-resident & XCD-local (proj batch remap). Nontemporal idx/out.
// ---------------------------------------------------------------------------
__global__ __launch_bounds__(256) void gather_dot_kernel(
    const unsigned short* __restrict__ tkb, const unsigned short* __restrict__ tqb,
    const int* __restrict__ idx, float* __restrict__ out)
{
    const long long NK  = (long long)NNODES * KNBR;     // 262144 per batch
    const long long BNK = NK * BATCH;                   // 2097152 total

    const int bat  = blockIdx.x & 7;
    const int blk  = blockIdx.x >> 3;                   // 0..255
    const int tid  = threadIdx.x;
    const int lane = tid & 63;
    const int j    = tid & 3;                           // uint4 column in row

    const uint4* tb_k = (const uint4*)(tkb + (long long)bat * NNODES * DOUT);
    const uint4* tb_q = (const uint4*)(tqb + (long long)bat * NNODES * DOUT);

    const long long base = (long long)bat * NK + (long long)blk * 256 + tid;

    // All idx loads up-front: 8 independent coalesced nontemporal loads.
    int xi[4], yi[4];
#pragma unroll
    for (int c = 0; c < 4; ++c) {
        const long long o = base + (long long)c * 65536;
        xi[c] = __builtin_nontemporal_load(&idx[BNK + o]);        // channel 1
        yi[c] = __builtin_nontemporal_load(&idx[2 * BNK + o]);    // channel 2
    }

#pragma unroll
    for (int c = 0; c < 4; ++c) {
        float r0, r1, r2, r3;
#pragma unroll
        for (int p = 0; p < 4; ++p) {
            const int xp = __shfl(xi[c], (lane & ~3) | p);   // quad-owner bcast
            const int yp = __shfl(yi[c], (lane & ~3) | p);
            const uint4 x = tb_k[(long long)xp * 4 + j];
            const uint4 y = tb_q[(long long)yp * 4 + j];
            float s = dot2bf(x.x, y.x) + dot2bf(x.y, y.y)
                    + dot2bf(x.z, y.z) + dot2bf(x.w, y.w);
            s += __shfl_xor(s, 1);
            s += __shfl_xor(s, 2);   // all 4 lanes hold the full 32-dim sum
            if      (p == 0) r0 = s;
            else if (p == 1) r1 = s;
            else if (p == 2) r2 = s;
            else             r3 = s;
        }
        // lane j stores pass-j's result -> dense contiguous store
        const float v = (j == 0) ? r0 : (j == 1) ? r1 : (j == 2) ? r2 : r3;
        __builtin_nontemporal_store(v * 0.17677669529663687f,
                                    &out[base + (long long)c * 65536]);
    }
}

// ---------------------------------------------------------------------------
extern "C" void kernel_launch(void* const* d_in, const int* in_sizes, int n_in,
                              void* d_out, int out_size, void* d_ws, size_t ws_size,
                              hipStream_t stream)
{
    const float* feats = (const float*)d_in[0];
    const float* kw    = (const float*)d_in[1];
    const float* kb    = (const float*)d_in[2];
    const float* qw    = (const float*)d_in[3];
    const float* qb    = (const float*)d_in[4];
    const int*   idx   = (const int*)d_in[5];
    float*       out   = (float*)d_out;

    // Workspace: two bf16 tables [B*N, 32] = 8 MB each
    unsigned short* tkb = (unsigned short*)d_ws;
    unsigned short* tqb = tkb + (long long)NROWS * DOUT;

    proj_kernel<<<NROWS / 128, 256, 0, stream>>>(feats, kw, kb, qw, qb, tkb, tqb);
    gather_dot_kernel<<<2048, 256, 0, stream>>>(tkb, tqb, idx, out);
}